// Round 1
// baseline (1225.401 us; speedup 1.0000x reference)
//
#include <hip/hip_runtime.h>

#define INCH 128
#define C1   16
#define C2   64

// ---------------- init: zero accumulators, deg starts at 1 (self loop) -----
__global__ void init_kernel(float* __restrict__ deg,
                            float* __restrict__ agg1,
                            float* __restrict__ agg2, int n) {
    int tid = blockIdx.x * blockDim.x + threadIdx.x;
    if (tid < n * C2) agg2[tid] = 0.0f;
    if (tid < n * C1) agg1[tid] = 0.0f;
    if (tid < n)      deg[tid]  = 1.0f;   // self loop contributes 1
}

// ---------------- degree: scatter-count col --------------------------------
__global__ void deg_kernel(const int* __restrict__ col,
                           float* __restrict__ deg, int e) {
    int tid = blockIdx.x * blockDim.x + threadIdx.x;
    if (tid < e) atomicAdd(&deg[col[tid]], 1.0f);
}

__global__ void invsqrt_kernel(const float* __restrict__ deg,
                               float* __restrict__ inv, int n) {
    int tid = blockIdx.x * blockDim.x + threadIdx.x;
    if (tid < n) inv[tid] = rsqrtf(deg[tid]);   // deg >= 1 always
}

// ---------------- linear1: xW1 = x@W1, xT1 = x@t1_W + t1_b (128 -> 16) -----
// block = 256 threads = 16 nodes x 16 ch. Weights + x tile staged in LDS.
__global__ __launch_bounds__(256) void linear1_kernel(
    const float* __restrict__ x, const float* __restrict__ W1,
    const float* __restrict__ T1, const float* __restrict__ t1b,
    float* __restrict__ xW1, float* __restrict__ xT1, int n)
{
    __shared__ float Wc[INCH][32];        // [:,0:16]=W1, [:,16:32]=t1_W
    __shared__ float xs[16][INCH + 4];    // +4 pad: breaks bank aliasing, keeps 16B align
    int tid = threadIdx.x;

    for (int i = tid; i < INCH * C1; i += 256) {
        int k = i / C1, c = i % C1;
        Wc[k][c]      = W1[i];
        Wc[k][c + 16] = T1[i];
    }
    int node0 = blockIdx.x * 16;
    // x tile: 16 rows x 128 = 512 float4, coalesced
    for (int i = tid; i < 16 * (INCH / 4); i += 256) {
        int r = i / (INCH / 4);
        int cc = i % (INCH / 4);
        int node = node0 + r;
        float4 v = make_float4(0.f, 0.f, 0.f, 0.f);
        if (node < n) v = ((const float4*)x)[(size_t)node * (INCH / 4) + cc];
        ((float4*)&xs[r][0])[cc] = v;
    }
    __syncthreads();

    int ch = tid & 15, nl = tid >> 4;
    int node = node0 + nl;
    if (node >= n) return;
    float a1 = 0.f, a2 = 0.f;
    #pragma unroll
    for (int k = 0; k < INCH; ++k) {
        float xv = xs[nl][k];
        a1 += xv * Wc[k][ch];
        a2 += xv * Wc[k][ch + 16];
    }
    xW1[node * C1 + ch] = a1;
    xT1[node * C1 + ch] = a2 + t1b[ch];
}

// ---------------- agg1: scatter edges, 16 ch per edge ----------------------
// thread = e*16 + ch : wave = 4 edges, coalesced gather + coalesced atomics
__global__ void agg1_kernel(const int* __restrict__ row, const int* __restrict__ col,
                            const float* __restrict__ inv, const float* __restrict__ xW1,
                            float* __restrict__ agg1, int total)
{
    int tid = blockIdx.x * blockDim.x + threadIdx.x;
    if (tid >= total) return;
    int e = tid >> 4, ch = tid & 15;
    int r = row[e], c = col[e];
    float norm = inv[r] * inv[c];
    atomicAdd(&agg1[c * C1 + ch], xW1[r * C1 + ch] * norm);
}

// ---------------- epi1: h = relu(agg1 + selfloop + b1) + identity1 ---------
__global__ void epi1_kernel(const float* __restrict__ agg1, const float* __restrict__ xW1,
                            const float* __restrict__ xT1, const float* __restrict__ b1,
                            const float* __restrict__ inv, float* __restrict__ h, int n)
{
    int tid = blockIdx.x * blockDim.x + threadIdx.x;
    if (tid >= n * C1) return;
    int i = tid >> 4, ch = tid & 15;
    float is = inv[i];
    float v = agg1[tid] + xW1[tid] * is * is + b1[ch];
    h[tid] = fmaxf(v, 0.f) + xT1[tid];
}

// ---------------- linear2: hW2 = h@W2, out = h@t2_W + t2_b (16 -> 64) ------
// block = 256 threads = 4 nodes x 64 ch
__global__ __launch_bounds__(256) void linear2_kernel(
    const float* __restrict__ h, const float* __restrict__ W2,
    const float* __restrict__ T2, const float* __restrict__ t2b,
    float* __restrict__ hW2, float* __restrict__ out, int n)
{
    __shared__ float Wc[C1][128];   // [:,0:64]=W2, [:,64:128]=t2_W
    __shared__ float hs[4][C1];
    int tid = threadIdx.x;

    for (int i = tid; i < C1 * C2; i += 256) {
        int k = i / C2, c = i % C2;
        Wc[k][c]      = W2[i];
        Wc[k][c + 64] = T2[i];
    }
    int node0 = blockIdx.x * 4;
    if (tid < 4 * C1) {
        int r = tid / C1, k = tid % C1;
        int node = node0 + r;
        hs[r][k] = (node < n) ? h[node * C1 + k] : 0.f;
    }
    __syncthreads();

    int ch = tid & 63, nl = tid >> 6;
    int node = node0 + nl;
    if (node >= n) return;
    float a1 = 0.f, a2 = 0.f;
    #pragma unroll
    for (int k = 0; k < C1; ++k) {
        float hv = hs[nl][k];
        a1 += hv * Wc[k][ch];
        a2 += hv * Wc[k][ch + 64];
    }
    hW2[node * C2 + ch] = a1;
    out[node * C2 + ch] = a2 + t2b[ch];   // identity2 written straight to d_out
}

// ---------------- agg2: scatter edges, 64 ch per edge ----------------------
// thread = e*64 + ch : wave = exactly 1 edge (uniform index loads broadcast)
__global__ void agg2_kernel(const int* __restrict__ row, const int* __restrict__ col,
                            const float* __restrict__ inv, const float* __restrict__ hW2,
                            float* __restrict__ agg2, int total)
{
    int tid = blockIdx.x * blockDim.x + threadIdx.x;
    if (tid >= total) return;
    int e = tid >> 6, ch = tid & 63;
    int r = row[e], c = col[e];
    float norm = inv[r] * inv[c];
    atomicAdd(&agg2[c * C2 + ch], hW2[r * C2 + ch] * norm);
}

// ---------------- epi2: out = relu(agg2 + selfloop + b2) + identity2 -------
__global__ void epi2_kernel(const float* __restrict__ agg2, const float* __restrict__ hW2,
                            const float* __restrict__ b2, const float* __restrict__ inv,
                            float* __restrict__ out, int n)
{
    int tid = blockIdx.x * blockDim.x + threadIdx.x;
    if (tid >= n * C2) return;
    int i = tid >> 6, ch = tid & 63;
    float is = inv[i];
    float v = agg2[tid] + hW2[tid] * is * is + b2[ch];
    out[tid] = fmaxf(v, 0.f) + out[tid];
}

extern "C" void kernel_launch(void* const* d_in, const int* in_sizes, int n_in,
                              void* d_out, int out_size, void* d_ws, size_t ws_size,
                              hipStream_t stream) {
    const float* x   = (const float*)d_in[0];
    const int*   ei  = (const int*)d_in[1];
    const float* W1  = (const float*)d_in[2];
    const float* b1  = (const float*)d_in[3];
    const float* W2  = (const float*)d_in[4];
    const float* b2  = (const float*)d_in[5];
    const float* T1  = (const float*)d_in[6];
    const float* t1b = (const float*)d_in[7];
    const float* T2  = (const float*)d_in[8];
    const float* t2b = (const float*)d_in[9];
    float* out = (float*)d_out;

    const int n = in_sizes[0] / INCH;       // 100000
    const int e = in_sizes[1] / 2;          // 3200000
    const int* row = ei;
    const int* col = ei + e;

    // workspace layout (floats)
    float* ws   = (float*)d_ws;
    float* deg  = ws;                        // n
    float* inv  = deg  + n;                  // n
    float* xW1  = inv  + n;                  // n*16
    float* xT1  = xW1  + (size_t)n * C1;     // n*16
    float* agg1 = xT1  + (size_t)n * C1;     // n*16
    float* h    = agg1 + (size_t)n * C1;     // n*16
    float* hW2  = h    + (size_t)n * C1;     // n*64
    float* agg2 = hW2  + (size_t)n * C2;     // n*64

    const int B = 256;
    init_kernel<<<(n * C2 + B - 1) / B, B, 0, stream>>>(deg, agg1, agg2, n);
    deg_kernel<<<(e + B - 1) / B, B, 0, stream>>>(col, deg, e);
    invsqrt_kernel<<<(n + B - 1) / B, B, 0, stream>>>(deg, inv, n);

    linear1_kernel<<<(n + 15) / 16, B, 0, stream>>>(x, W1, T1, t1b, xW1, xT1, n);
    agg1_kernel<<<((size_t)e * C1 + B - 1) / B, B, 0, stream>>>(row, col, inv, xW1, agg1, e * C1);
    epi1_kernel<<<(n * C1 + B - 1) / B, B, 0, stream>>>(agg1, xW1, xT1, b1, inv, h, n);

    linear2_kernel<<<(n + 3) / 4, B, 0, stream>>>(h, W2, T2, t2b, hW2, out, n);
    agg2_kernel<<<((size_t)e * C2 + B - 1) / B, B, 0, stream>>>(row, col, inv, hW2, agg2, e * C2);
    epi2_kernel<<<(n * C2 + B - 1) / B, B, 0, stream>>>(agg2, hW2, b2, inv, out, n);
}

// Round 2
// 715.688 us; speedup vs baseline: 1.7122x; 1.7122x over previous
//
#include <hip/hip_runtime.h>

#define INCH 128
#define C1   16
#define C2   64
#define SCAN_B 512   // elements per scan block

// ---------------- init: zero cnt + fill ------------------------------------
__global__ void init_kernel(int* __restrict__ cnt, int* __restrict__ fill, int n) {
    int tid = blockIdx.x * blockDim.x + threadIdx.x;
    if (tid < n) { cnt[tid] = 0; fill[tid] = 0; }
}

// ---------------- histogram: in-degree at col ------------------------------
__global__ void hist_kernel(const int* __restrict__ col, int* __restrict__ cnt, int e) {
    int tid = blockIdx.x * blockDim.x + threadIdx.x;
    if (tid < e) atomicAdd(&cnt[col[tid]], 1);
}

// ---------------- inv_sqrt of (cnt + 1 self loop) --------------------------
__global__ void invsqrt_kernel(const int* __restrict__ cnt, float* __restrict__ inv, int n) {
    int tid = blockIdx.x * blockDim.x + threadIdx.x;
    if (tid < n) inv[tid] = rsqrtf((float)(cnt[tid] + 1));
}

// ---------------- 2-level exclusive scan of cnt -> offs --------------------
__global__ __launch_bounds__(SCAN_B) void scan_local_kernel(
    const int* __restrict__ cnt, int* __restrict__ offs, int* __restrict__ bsum, int n)
{
    __shared__ int tmp[SCAN_B];
    int gid = blockIdx.x * SCAN_B + threadIdx.x;
    int v = (gid < n) ? cnt[gid] : 0;
    tmp[threadIdx.x] = v;
    __syncthreads();
    for (int off = 1; off < SCAN_B; off <<= 1) {
        int t = (threadIdx.x >= off) ? tmp[threadIdx.x - off] : 0;
        __syncthreads();
        tmp[threadIdx.x] += t;
        __syncthreads();
    }
    if (gid < n) offs[gid] = tmp[threadIdx.x] - v;        // exclusive
    if (threadIdx.x == SCAN_B - 1) bsum[blockIdx.x] = tmp[SCAN_B - 1];
}

__global__ __launch_bounds__(256) void scan_bsum_kernel(int* __restrict__ bsum, int nb) {
    __shared__ int tmp[256];
    int v = (threadIdx.x < nb) ? bsum[threadIdx.x] : 0;
    tmp[threadIdx.x] = v;
    __syncthreads();
    for (int off = 1; off < 256; off <<= 1) {
        int t = (threadIdx.x >= off) ? tmp[threadIdx.x - off] : 0;
        __syncthreads();
        tmp[threadIdx.x] += t;
        __syncthreads();
    }
    if (threadIdx.x < nb) bsum[threadIdx.x] = tmp[threadIdx.x] - v;  // exclusive
}

__global__ __launch_bounds__(SCAN_B) void scan_add_kernel(
    int* __restrict__ offs, const int* __restrict__ bsum, int n)
{
    int gid = blockIdx.x * SCAN_B + threadIdx.x;
    if (gid < n) offs[gid] += bsum[blockIdx.x];
}

// ---------------- scatter edges into CSR order -----------------------------
// sorted[p] = { src, bits(inv[src]) } for edges grouped by dest
__global__ void scatter_kernel(const int* __restrict__ row, const int* __restrict__ col,
                               const float* __restrict__ inv, const int* __restrict__ offs,
                               int* __restrict__ fill, int2* __restrict__ sorted, int e)
{
    int tid = blockIdx.x * blockDim.x + threadIdx.x;
    if (tid >= e) return;
    int r = row[tid], c = col[tid];
    int p = offs[c] + atomicAdd(&fill[c], 1);
    sorted[p] = make_int2(r, __float_as_int(inv[r]));
}

// ---------------- linear1: xW1 = x@W1, xT1 = x@t1_W + t1_b (128 -> 16) -----
__global__ __launch_bounds__(256) void linear1_kernel(
    const float* __restrict__ x, const float* __restrict__ W1,
    const float* __restrict__ T1, const float* __restrict__ t1b,
    float* __restrict__ xW1, float* __restrict__ xT1, int n)
{
    __shared__ float Wc[INCH][32];        // [:,0:16]=W1, [:,16:32]=t1_W
    __shared__ float xs[16][INCH + 4];
    int tid = threadIdx.x;

    for (int i = tid; i < INCH * C1; i += 256) {
        int k = i / C1, c = i % C1;
        Wc[k][c]      = W1[i];
        Wc[k][c + 16] = T1[i];
    }
    int node0 = blockIdx.x * 16;
    for (int i = tid; i < 16 * (INCH / 4); i += 256) {
        int r = i / (INCH / 4);
        int cc = i % (INCH / 4);
        int node = node0 + r;
        float4 v = make_float4(0.f, 0.f, 0.f, 0.f);
        if (node < n) v = ((const float4*)x)[(size_t)node * (INCH / 4) + cc];
        ((float4*)&xs[r][0])[cc] = v;
    }
    __syncthreads();

    int ch = tid & 15, nl = tid >> 4;
    int node = node0 + nl;
    if (node >= n) return;
    float a1 = 0.f, a2 = 0.f;
    #pragma unroll
    for (int k = 0; k < INCH; ++k) {
        float xv = xs[nl][k];
        a1 += xv * Wc[k][ch];
        a2 += xv * Wc[k][ch + 16];
    }
    xW1[node * C1 + ch] = a1;
    xT1[node * C1 + ch] = a2 + t1b[ch];
}

// ---------------- agg1 CSR + fused epilogue1 -------------------------------
// 16 lanes per node (4 nodes/wave, 16 nodes/block)
__global__ __launch_bounds__(256) void agg1_csr_kernel(
    const int2* __restrict__ sorted, const int* __restrict__ offs,
    const int* __restrict__ cnt, const float* __restrict__ inv,
    const float* __restrict__ xW1, const float* __restrict__ xT1,
    const float* __restrict__ b1, float* __restrict__ h, int n)
{
    int node = blockIdx.x * 16 + (threadIdx.x >> 4);
    int ch = threadIdx.x & 15;
    if (node >= n) return;
    int beg = offs[node], end = beg + cnt[node];
    float ic = inv[node];
    float acc0 = 0.f, acc1 = 0.f;
    int p = beg;
    for (; p + 1 < end; p += 2) {
        int2 e0 = sorted[p], e1 = sorted[p + 1];
        acc0 += xW1[e0.x * C1 + ch] * (__int_as_float(e0.y) * ic);
        acc1 += xW1[e1.x * C1 + ch] * (__int_as_float(e1.y) * ic);
    }
    if (p < end) {
        int2 e0 = sorted[p];
        acc0 += xW1[e0.x * C1 + ch] * (__int_as_float(e0.y) * ic);
    }
    int idx = node * C1 + ch;
    float v = acc0 + acc1 + xW1[idx] * ic * ic + b1[ch];
    h[idx] = fmaxf(v, 0.f) + xT1[idx];
}

// ---------------- linear2: hW2 = h@W2, out = h@t2_W + t2_b (16 -> 64) ------
__global__ __launch_bounds__(256) void linear2_kernel(
    const float* __restrict__ h, const float* __restrict__ W2,
    const float* __restrict__ T2, const float* __restrict__ t2b,
    float* __restrict__ hW2, float* __restrict__ out, int n)
{
    __shared__ float Wc[C1][128];   // [:,0:64]=W2, [:,64:128]=t2_W
    __shared__ float hs[4][C1];
    int tid = threadIdx.x;

    for (int i = tid; i < C1 * C2; i += 256) {
        int k = i / C2, c = i % C2;
        Wc[k][c]      = W2[i];
        Wc[k][c + 64] = T2[i];
    }
    int node0 = blockIdx.x * 4;
    if (tid < 4 * C1) {
        int r = tid / C1, k = tid % C1;
        int node = node0 + r;
        hs[r][k] = (node < n) ? h[node * C1 + k] : 0.f;
    }
    __syncthreads();

    int ch = tid & 63, nl = tid >> 6;
    int node = node0 + nl;
    if (node >= n) return;
    float a1 = 0.f, a2 = 0.f;
    #pragma unroll
    for (int k = 0; k < C1; ++k) {
        float hv = hs[nl][k];
        a1 += hv * Wc[k][ch];
        a2 += hv * Wc[k][ch + 64];
    }
    hW2[node * C2 + ch] = a1;
    out[node * C2 + ch] = a2 + t2b[ch];   // identity2 straight to d_out
}

// ---------------- agg2 CSR + fused epilogue2 -------------------------------
// 64 lanes per node (1 node/wave, 4 nodes/block)
__global__ __launch_bounds__(256) void agg2_csr_kernel(
    const int2* __restrict__ sorted, const int* __restrict__ offs,
    const int* __restrict__ cnt, const float* __restrict__ inv,
    const float* __restrict__ hW2, const float* __restrict__ b2,
    float* __restrict__ out, int n)
{
    int node = blockIdx.x * 4 + (threadIdx.x >> 6);
    int ch = threadIdx.x & 63;
    if (node >= n) return;
    int beg = offs[node], end = beg + cnt[node];
    float ic = inv[node];
    float acc0 = 0.f, acc1 = 0.f;
    int p = beg;
    for (; p + 1 < end; p += 2) {
        int2 e0 = sorted[p], e1 = sorted[p + 1];
        acc0 += hW2[e0.x * C2 + ch] * (__int_as_float(e0.y) * ic);
        acc1 += hW2[e1.x * C2 + ch] * (__int_as_float(e1.y) * ic);
    }
    if (p < end) {
        int2 e0 = sorted[p];
        acc0 += hW2[e0.x * C2 + ch] * (__int_as_float(e0.y) * ic);
    }
    int idx = node * C2 + ch;
    float v = acc0 + acc1 + hW2[idx] * ic * ic + b2[ch];
    out[idx] = fmaxf(v, 0.f) + out[idx];
}

extern "C" void kernel_launch(void* const* d_in, const int* in_sizes, int n_in,
                              void* d_out, int out_size, void* d_ws, size_t ws_size,
                              hipStream_t stream) {
    const float* x   = (const float*)d_in[0];
    const int*   ei  = (const int*)d_in[1];
    const float* W1  = (const float*)d_in[2];
    const float* b1  = (const float*)d_in[3];
    const float* W2  = (const float*)d_in[4];
    const float* b2  = (const float*)d_in[5];
    const float* T1  = (const float*)d_in[6];
    const float* t1b = (const float*)d_in[7];
    const float* T2  = (const float*)d_in[8];
    const float* t2b = (const float*)d_in[9];
    float* out = (float*)d_out;

    const int n = in_sizes[0] / INCH;       // 100000
    const int e = in_sizes[1] / 2;          // 3200000
    const int* row = ei;
    const int* col = ei + e;

    // workspace layout (8B-aligned first)
    char* ws = (char*)d_ws;
    int2*  sorted = (int2*)ws;                        ws += (size_t)e * sizeof(int2);   // 25.6 MB
    int*   cnt    = (int*)ws;                         ws += (size_t)n * 4;
    int*   fill   = (int*)ws;                         ws += (size_t)n * 4;
    int*   offs   = (int*)ws;                         ws += (size_t)n * 4;
    int*   bsum   = (int*)ws;                         ws += 256 * 4;
    float* inv    = (float*)ws;                       ws += (size_t)n * 4;
    float* xW1    = (float*)ws;                       ws += (size_t)n * C1 * 4;
    float* xT1    = (float*)ws;                       ws += (size_t)n * C1 * 4;
    float* h      = (float*)ws;                       ws += (size_t)n * C1 * 4;
    float* hW2    = (float*)ws;                       ws += (size_t)n * C2 * 4;

    const int B = 256;
    const int nb_scan = (n + SCAN_B - 1) / SCAN_B;    // 196

    init_kernel   <<<(n + B - 1) / B, B, 0, stream>>>(cnt, fill, n);
    hist_kernel   <<<(e + B - 1) / B, B, 0, stream>>>(col, cnt, e);
    invsqrt_kernel<<<(n + B - 1) / B, B, 0, stream>>>(cnt, inv, n);

    scan_local_kernel<<<nb_scan, SCAN_B, 0, stream>>>(cnt, offs, bsum, n);
    scan_bsum_kernel <<<1, 256, 0, stream>>>(bsum, nb_scan);
    scan_add_kernel  <<<nb_scan, SCAN_B, 0, stream>>>(offs, bsum, n);

    scatter_kernel<<<(e + B - 1) / B, B, 0, stream>>>(row, col, inv, offs, fill, sorted, e);

    linear1_kernel <<<(n + 15) / 16, B, 0, stream>>>(x, W1, T1, t1b, xW1, xT1, n);
    agg1_csr_kernel<<<(n + 15) / 16, B, 0, stream>>>(sorted, offs, cnt, inv, xW1, xT1, b1, h, n);

    linear2_kernel <<<(n + 3) / 4, B, 0, stream>>>(h, W2, T2, t2b, hW2, out, n);
    agg2_csr_kernel<<<(n + 3) / 4, B, 0, stream>>>(sorted, offs, cnt, inv, hW2, b2, out, n);
}

// Round 3
// 592.823 us; speedup vs baseline: 2.0671x; 1.2073x over previous
//
#include <hip/hip_runtime.h>

#define INCH 128
#define C1   16
#define C2   64
#define SCAN_B 512   // elements per scan block

// ---------------- init: zero cnt + fill ------------------------------------
__global__ void init_kernel(int* __restrict__ cnt, int* __restrict__ fill, int n) {
    int tid = blockIdx.x * blockDim.x + threadIdx.x;
    if (tid < n) { cnt[tid] = 0; fill[tid] = 0; }
}

// ---------------- histogram: in-degree at col ------------------------------
__global__ void hist_kernel(const int* __restrict__ col, int* __restrict__ cnt, int e) {
    int tid = blockIdx.x * blockDim.x + threadIdx.x;
    if (tid < e) atomicAdd(&cnt[col[tid]], 1);
}

// ---------------- inv_sqrt of (cnt + 1 self loop) --------------------------
__global__ void invsqrt_kernel(const int* __restrict__ cnt, float* __restrict__ inv, int n) {
    int tid = blockIdx.x * blockDim.x + threadIdx.x;
    if (tid < n) inv[tid] = rsqrtf((float)(cnt[tid] + 1));
}

// ---------------- 2-level exclusive scan of cnt -> offs --------------------
__global__ __launch_bounds__(SCAN_B) void scan_local_kernel(
    const int* __restrict__ cnt, int* __restrict__ offs, int* __restrict__ bsum, int n)
{
    __shared__ int tmp[SCAN_B];
    int gid = blockIdx.x * SCAN_B + threadIdx.x;
    int v = (gid < n) ? cnt[gid] : 0;
    tmp[threadIdx.x] = v;
    __syncthreads();
    for (int off = 1; off < SCAN_B; off <<= 1) {
        int t = (threadIdx.x >= off) ? tmp[threadIdx.x - off] : 0;
        __syncthreads();
        tmp[threadIdx.x] += t;
        __syncthreads();
    }
    if (gid < n) offs[gid] = tmp[threadIdx.x] - v;        // exclusive
    if (threadIdx.x == SCAN_B - 1) bsum[blockIdx.x] = tmp[SCAN_B - 1];
}

__global__ __launch_bounds__(256) void scan_bsum_kernel(int* __restrict__ bsum, int nb) {
    __shared__ int tmp[256];
    int v = (threadIdx.x < nb) ? bsum[threadIdx.x] : 0;
    tmp[threadIdx.x] = v;
    __syncthreads();
    for (int off = 1; off < 256; off <<= 1) {
        int t = (threadIdx.x >= off) ? tmp[threadIdx.x - off] : 0;
        __syncthreads();
        tmp[threadIdx.x] += t;
        __syncthreads();
    }
    if (threadIdx.x < nb) bsum[threadIdx.x] = tmp[threadIdx.x] - v;  // exclusive
}

__global__ __launch_bounds__(SCAN_B) void scan_add_kernel(
    int* __restrict__ offs, const int* __restrict__ bsum, int n)
{
    int gid = blockIdx.x * SCAN_B + threadIdx.x;
    if (gid < n) offs[gid] += bsum[blockIdx.x];
}

// ---------------- scatter edges into CSR order (src only, 4 B/edge) --------
__global__ void scatter_kernel(const int* __restrict__ row, const int* __restrict__ col,
                               const int* __restrict__ offs,
                               int* __restrict__ fill, int* __restrict__ sorted, int e)
{
    int tid = blockIdx.x * blockDim.x + threadIdx.x;
    if (tid >= e) return;
    int r = row[tid], c = col[tid];
    int p = offs[c] + atomicAdd(&fill[c], 1);
    sorted[p] = r;
}

// ---------------- linear1: xW1s = (x@W1)*inv, xT1 = x@t1_W + t1_b ----------
__global__ __launch_bounds__(256) void linear1_kernel(
    const float* __restrict__ x, const float* __restrict__ W1,
    const float* __restrict__ T1, const float* __restrict__ t1b,
    const float* __restrict__ inv,
    float* __restrict__ xW1s, float* __restrict__ xT1, int n)
{
    __shared__ float Wc[INCH][32];        // [:,0:16]=W1, [:,16:32]=t1_W
    __shared__ float xs[16][INCH + 4];
    int tid = threadIdx.x;

    for (int i = tid; i < INCH * C1; i += 256) {
        int k = i / C1, c = i % C1;
        Wc[k][c]      = W1[i];
        Wc[k][c + 16] = T1[i];
    }
    int node0 = blockIdx.x * 16;
    for (int i = tid; i < 16 * (INCH / 4); i += 256) {
        int r = i / (INCH / 4);
        int cc = i % (INCH / 4);
        int node = node0 + r;
        float4 v = make_float4(0.f, 0.f, 0.f, 0.f);
        if (node < n) v = ((const float4*)x)[(size_t)node * (INCH / 4) + cc];
        ((float4*)&xs[r][0])[cc] = v;
    }
    __syncthreads();

    int ch = tid & 15, nl = tid >> 4;
    int node = node0 + nl;
    if (node >= n) return;
    float a1 = 0.f, a2 = 0.f;
    #pragma unroll
    for (int k = 0; k < INCH; ++k) {
        float xv = xs[nl][k];
        a1 += xv * Wc[k][ch];
        a2 += xv * Wc[k][ch + 16];
    }
    xW1s[node * C1 + ch] = a1 * inv[node];   // pre-scaled by inv[src]
    xT1[node * C1 + ch]  = a2 + t1b[ch];
}

// ---------------- agg1 CSR + fused epilogue1 -------------------------------
// 16 lanes per node. acc = sum(xW1s[src]); v = (acc + xW1s[i]) * ic + b1
// h = relu(v) + xT1 ; hs = h * ic  (pre-scaled for layer 2)
__global__ __launch_bounds__(256) void agg1_csr_kernel(
    const int* __restrict__ sorted, const int* __restrict__ offs,
    const int* __restrict__ cnt, const float* __restrict__ inv,
    const float* __restrict__ xW1s, const float* __restrict__ xT1,
    const float* __restrict__ b1,
    float* __restrict__ h, float* __restrict__ hs, int n)
{
    int node = blockIdx.x * 16 + (threadIdx.x >> 4);
    int ch = threadIdx.x & 15;
    if (node >= n) return;
    int beg = offs[node], end = beg + cnt[node];
    float ic = inv[node];
    float a0 = 0.f, a1 = 0.f, a2 = 0.f, a3 = 0.f;
    int p = beg;
    for (; p + 3 < end; p += 4) {
        int s0 = sorted[p], s1 = sorted[p + 1], s2 = sorted[p + 2], s3 = sorted[p + 3];
        a0 += xW1s[s0 * C1 + ch];
        a1 += xW1s[s1 * C1 + ch];
        a2 += xW1s[s2 * C1 + ch];
        a3 += xW1s[s3 * C1 + ch];
    }
    for (; p < end; ++p) a0 += xW1s[sorted[p] * C1 + ch];
    int idx = node * C1 + ch;
    float v = (a0 + a1 + a2 + a3 + xW1s[idx]) * ic + b1[ch];
    float hv = fmaxf(v, 0.f) + xT1[idx];
    h[idx]  = hv;
    hs[idx] = hv * ic;
}

// ---------------- agg2 fused: CSR agg (16ch) + 16->64 linears + epilogue ---
// Phase 1: 16 lanes/node aggregate hs -> LDS. Phase 2: 64 lanes/node compute
// out = relu(aggTot@W2 + b2) + h@t2_W + t2b  (4 outputs per thread)
__global__ __launch_bounds__(256) void agg2_fused_kernel(
    const int* __restrict__ sorted, const int* __restrict__ offs,
    const int* __restrict__ cnt, const float* __restrict__ inv,
    const float* __restrict__ hs, const float* __restrict__ h,
    const float* __restrict__ W2, const float* __restrict__ T2,
    const float* __restrict__ b2, const float* __restrict__ t2b,
    float* __restrict__ out, int n)
{
    __shared__ float Wc[C1][128];     // [:,0:64]=W2, [:,64:128]=t2_W
    __shared__ float acc_s[16][C1];   // aggregated (incl. self, *ic)
    __shared__ float h_s[16][C1];     // unscaled h for identity2
    int tid = threadIdx.x;

    for (int i = tid; i < C1 * 128; i += 256) {
        int k = i >> 7, c = i & 127;
        Wc[k][c] = (c < 64) ? W2[k * C2 + c] : T2[k * C2 + (c - 64)];
    }

    int nl = tid >> 4, ch = tid & 15;
    int node = blockIdx.x * 16 + nl;
    float acc = 0.f, hval = 0.f;
    if (node < n) {
        int beg = offs[node], end = beg + cnt[node];
        float a0 = 0.f, a1 = 0.f, a2 = 0.f, a3 = 0.f;
        int p = beg;
        for (; p + 3 < end; p += 4) {
            int s0 = sorted[p], s1 = sorted[p + 1], s2 = sorted[p + 2], s3 = sorted[p + 3];
            a0 += hs[s0 * C1 + ch];
            a1 += hs[s1 * C1 + ch];
            a2 += hs[s2 * C1 + ch];
            a3 += hs[s3 * C1 + ch];
        }
        for (; p < end; ++p) a0 += hs[sorted[p] * C1 + ch];
        int idx = node * C1 + ch;
        acc = (a0 + a1 + a2 + a3 + hs[idx]) * inv[node];
        hval = h[idx];
    }
    acc_s[nl][ch] = acc;
    h_s[nl][ch]   = hval;
    __syncthreads();

    int och = tid & 63, grp = tid >> 6;
    #pragma unroll
    for (int q = 0; q < 4; ++q) {
        int nl2 = grp * 4 + q;
        int node2 = blockIdx.x * 16 + nl2;
        if (node2 >= n) continue;
        float s1v = b2[och], s2v = t2b[och];
        #pragma unroll
        for (int k = 0; k < C1; ++k) {
            s1v += acc_s[nl2][k] * Wc[k][och];
            s2v += h_s[nl2][k]   * Wc[k][och + 64];
        }
        out[node2 * C2 + och] = fmaxf(s1v, 0.f) + s2v;
    }
}

extern "C" void kernel_launch(void* const* d_in, const int* in_sizes, int n_in,
                              void* d_out, int out_size, void* d_ws, size_t ws_size,
                              hipStream_t stream) {
    const float* x   = (const float*)d_in[0];
    const int*   ei  = (const int*)d_in[1];
    const float* W1  = (const float*)d_in[2];
    const float* b1  = (const float*)d_in[3];
    const float* W2  = (const float*)d_in[4];
    const float* b2  = (const float*)d_in[5];
    const float* T1  = (const float*)d_in[6];
    const float* t1b = (const float*)d_in[7];
    const float* T2  = (const float*)d_in[8];
    const float* t2b = (const float*)d_in[9];
    float* out = (float*)d_out;

    const int n = in_sizes[0] / INCH;       // 100000
    const int e = in_sizes[1] / 2;          // 3200000
    const int* row = ei;
    const int* col = ei + e;

    // workspace layout
    char* ws = (char*)d_ws;
    int*   sorted = (int*)ws;                         ws += (size_t)e * 4;   // 12.8 MB
    int*   cnt    = (int*)ws;                         ws += (size_t)n * 4;
    int*   fill   = (int*)ws;                         ws += (size_t)n * 4;
    int*   offs   = (int*)ws;                         ws += (size_t)n * 4;
    int*   bsum   = (int*)ws;                         ws += 256 * 4;
    float* inv    = (float*)ws;                       ws += (size_t)n * 4;
    float* xW1s   = (float*)ws;                       ws += (size_t)n * C1 * 4;
    float* xT1    = (float*)ws;                       ws += (size_t)n * C1 * 4;
    float* h      = (float*)ws;                       ws += (size_t)n * C1 * 4;
    float* hs     = (float*)ws;                       ws += (size_t)n * C1 * 4;

    const int B = 256;
    const int nb_scan = (n + SCAN_B - 1) / SCAN_B;    // 196

    init_kernel   <<<(n + B - 1) / B, B, 0, stream>>>(cnt, fill, n);
    hist_kernel   <<<(e + B - 1) / B, B, 0, stream>>>(col, cnt, e);
    invsqrt_kernel<<<(n + B - 1) / B, B, 0, stream>>>(cnt, inv, n);

    scan_local_kernel<<<nb_scan, SCAN_B, 0, stream>>>(cnt, offs, bsum, n);
    scan_bsum_kernel <<<1, 256, 0, stream>>>(bsum, nb_scan);
    scan_add_kernel  <<<nb_scan, SCAN_B, 0, stream>>>(offs, bsum, n);

    scatter_kernel<<<(e + B - 1) / B, B, 0, stream>>>(row, col, offs, fill, sorted, e);

    linear1_kernel <<<(n + 15) / 16, B, 0, stream>>>(x, W1, T1, t1b, inv, xW1s, xT1, n);
    agg1_csr_kernel<<<(n + 15) / 16, B, 0, stream>>>(sorted, offs, cnt, inv, xW1s, xT1, b1, h, hs, n);

    agg2_fused_kernel<<<(n + 15) / 16, B, 0, stream>>>(sorted, offs, cnt, inv, hs, h,
                                                       W2, T2, b2, t2b, out, n);
}

// Round 4
// 543.487 us; speedup vs baseline: 2.2547x; 1.0908x over previous
//
#include <hip/hip_runtime.h>

#define INCH 128
#define C1   16
#define C2   64
#define SCAN_B 512   // elements per scan block
#define NRANGE 8     // dst-range partitions for scatter (XCD count)

typedef int iv4 __attribute__((ext_vector_type(4)));

// ---------------- init: zero cnt -------------------------------------------
__global__ void init_kernel(int* __restrict__ cnt, int n) {
    int tid = blockIdx.x * blockDim.x + threadIdx.x;
    if (tid < n) cnt[tid] = 0;
}

// ---------------- histogram: in-degree at col (nt reads) -------------------
__global__ void hist_kernel(const int* __restrict__ col, int* __restrict__ cnt, int e) {
    int tid = blockIdx.x * blockDim.x + threadIdx.x;
    int e4 = e >> 2;
    if (tid < e4) {
        iv4 c4 = __builtin_nontemporal_load((const iv4*)col + tid);
        atomicAdd(&cnt[c4.x], 1);
        atomicAdd(&cnt[c4.y], 1);
        atomicAdd(&cnt[c4.z], 1);
        atomicAdd(&cnt[c4.w], 1);
    }
    int rem = e4 * 4 + tid;
    if (tid < (e & 3)) atomicAdd(&cnt[col[rem]], 1);
}

// ---------------- inv_sqrt of (cnt + 1 self loop) --------------------------
__global__ void invsqrt_kernel(const int* __restrict__ cnt, float* __restrict__ inv, int n) {
    int tid = blockIdx.x * blockDim.x + threadIdx.x;
    if (tid < n) inv[tid] = rsqrtf((float)(cnt[tid] + 1));
}

// ---------------- 2-level exclusive scan of cnt -> offs --------------------
__global__ __launch_bounds__(SCAN_B) void scan_local_kernel(
    const int* __restrict__ cnt, int* __restrict__ offs, int* __restrict__ bsum, int n)
{
    __shared__ int tmp[SCAN_B];
    int gid = blockIdx.x * SCAN_B + threadIdx.x;
    int v = (gid < n) ? cnt[gid] : 0;
    tmp[threadIdx.x] = v;
    __syncthreads();
    for (int off = 1; off < SCAN_B; off <<= 1) {
        int t = (threadIdx.x >= off) ? tmp[threadIdx.x - off] : 0;
        __syncthreads();
        tmp[threadIdx.x] += t;
        __syncthreads();
    }
    if (gid < n) offs[gid] = tmp[threadIdx.x] - v;        // exclusive
    if (threadIdx.x == SCAN_B - 1) bsum[blockIdx.x] = tmp[SCAN_B - 1];
}

__global__ __launch_bounds__(256) void scan_bsum_kernel(int* __restrict__ bsum, int nb) {
    __shared__ int tmp[256];
    int v = (threadIdx.x < nb) ? bsum[threadIdx.x] : 0;
    tmp[threadIdx.x] = v;
    __syncthreads();
    for (int off = 1; off < 256; off <<= 1) {
        int t = (threadIdx.x >= off) ? tmp[threadIdx.x - off] : 0;
        __syncthreads();
        tmp[threadIdx.x] += t;
        __syncthreads();
    }
    if (threadIdx.x < nb) bsum[threadIdx.x] = tmp[threadIdx.x] - v;  // exclusive
}

// offs += bsum; cursor = offs (merged fill counter)
__global__ __launch_bounds__(SCAN_B) void scan_add_kernel(
    int* __restrict__ offs, int* __restrict__ cursor, const int* __restrict__ bsum, int n)
{
    int gid = blockIdx.x * SCAN_B + threadIdx.x;
    if (gid < n) {
        int v = offs[gid] + bsum[blockIdx.x];
        offs[gid] = v;
        cursor[gid] = v;
    }
}

// ---------------- dst-range-partitioned CSR scatter ------------------------
// block (slice s = blockIdx>>3, residue r = blockIdx&7): reads edge chunk s
// (non-temporal, stays out of L2), writes only edges with dst in range r.
// Residue r maps to one XCD under round-robin dispatch -> each output line is
// dirtied in ~1 L2 and written back once (correctness independent of mapping).
__global__ __launch_bounds__(256) void scatter_kernel(
    const int* __restrict__ row, const int* __restrict__ col,
    int* __restrict__ cursor, int* __restrict__ sorted,
    int e, int n, int nslices)
{
    int r = blockIdx.x & (NRANGE - 1);
    int s = blockIdx.x >> 3;
    int lo = (int)((long)n * r / NRANGE);
    int hi = (int)((long)n * (r + 1) / NRANGE);
    int e4 = e >> 2;
    long b0 = (long)s * e4 / nslices;
    long b1 = (long)(s + 1) * e4 / nslices;
    const iv4* row4 = (const iv4*)row;
    const iv4* col4 = (const iv4*)col;
    for (long i = b0 + threadIdx.x; i < b1; i += blockDim.x) {
        iv4 c4 = __builtin_nontemporal_load(&col4[i]);
        iv4 r4 = __builtin_nontemporal_load(&row4[i]);
        #pragma unroll
        for (int k = 0; k < 4; ++k) {
            int c = c4[k];
            if (c >= lo && c < hi) {
                int p = atomicAdd(&cursor[c], 1);
                sorted[p] = r4[k];
            }
        }
    }
    if (s == 0) {   // tail (e % 4), still range-filtered so each edge lands once
        for (int i = e4 * 4 + threadIdx.x; i < e; i += blockDim.x) {
            int c = col[i];
            if (c >= lo && c < hi) {
                int p = atomicAdd(&cursor[c], 1);
                sorted[p] = row[i];
            }
        }
    }
}

// ---------------- linear1: xW1s = (x@W1)*inv, xT1 = x@t1_W + t1_b ----------
__global__ __launch_bounds__(256) void linear1_kernel(
    const float* __restrict__ x, const float* __restrict__ W1,
    const float* __restrict__ T1, const float* __restrict__ t1b,
    const float* __restrict__ inv,
    float* __restrict__ xW1s, float* __restrict__ xT1, int n)
{
    __shared__ float Wc[INCH][32];        // [:,0:16]=W1, [:,16:32]=t1_W
    __shared__ float xs[16][INCH + 4];
    int tid = threadIdx.x;

    for (int i = tid; i < INCH * C1; i += 256) {
        int k = i / C1, c = i % C1;
        Wc[k][c]      = W1[i];
        Wc[k][c + 16] = T1[i];
    }
    int node0 = blockIdx.x * 16;
    for (int i = tid; i < 16 * (INCH / 4); i += 256) {
        int r = i / (INCH / 4);
        int cc = i % (INCH / 4);
        int node = node0 + r;
        float4 v = make_float4(0.f, 0.f, 0.f, 0.f);
        if (node < n) v = ((const float4*)x)[(size_t)node * (INCH / 4) + cc];
        ((float4*)&xs[r][0])[cc] = v;
    }
    __syncthreads();

    int ch = tid & 15, nl = tid >> 4;
    int node = node0 + nl;
    if (node >= n) return;
    float a1 = 0.f, a2 = 0.f;
    #pragma unroll
    for (int k = 0; k < INCH; ++k) {
        float xv = xs[nl][k];
        a1 += xv * Wc[k][ch];
        a2 += xv * Wc[k][ch + 16];
    }
    xW1s[node * C1 + ch] = a1 * inv[node];   // pre-scaled by inv[src]
    xT1[node * C1 + ch]  = a2 + t1b[ch];
}

// ---------------- agg1 CSR + fused epilogue1 -------------------------------
__global__ __launch_bounds__(256) void agg1_csr_kernel(
    const int* __restrict__ sorted, const int* __restrict__ offs,
    const int* __restrict__ cnt, const float* __restrict__ inv,
    const float* __restrict__ xW1s, const float* __restrict__ xT1,
    const float* __restrict__ b1,
    float* __restrict__ h, float* __restrict__ hs, int n)
{
    int node = blockIdx.x * 16 + (threadIdx.x >> 4);
    int ch = threadIdx.x & 15;
    if (node >= n) return;
    int beg = offs[node], end = beg + cnt[node];
    float ic = inv[node];
    float a0 = 0.f, a1 = 0.f, a2 = 0.f, a3 = 0.f;
    int p = beg;
    for (; p + 3 < end; p += 4) {
        int s0 = sorted[p], s1 = sorted[p + 1], s2 = sorted[p + 2], s3 = sorted[p + 3];
        a0 += xW1s[s0 * C1 + ch];
        a1 += xW1s[s1 * C1 + ch];
        a2 += xW1s[s2 * C1 + ch];
        a3 += xW1s[s3 * C1 + ch];
    }
    for (; p < end; ++p) a0 += xW1s[sorted[p] * C1 + ch];
    int idx = node * C1 + ch;
    float v = (a0 + a1 + a2 + a3 + xW1s[idx]) * ic + b1[ch];
    float hv = fmaxf(v, 0.f) + xT1[idx];
    h[idx]  = hv;
    hs[idx] = hv * ic;
}

// ---------------- agg2 fused: CSR agg (16ch) + 16->64 linears + epilogue ---
__global__ __launch_bounds__(256) void agg2_fused_kernel(
    const int* __restrict__ sorted, const int* __restrict__ offs,
    const int* __restrict__ cnt, const float* __restrict__ inv,
    const float* __restrict__ hs, const float* __restrict__ h,
    const float* __restrict__ W2, const float* __restrict__ T2,
    const float* __restrict__ b2, const float* __restrict__ t2b,
    float* __restrict__ out, int n)
{
    __shared__ float Wc[C1][128];     // [:,0:64]=W2, [:,64:128]=t2_W
    __shared__ float acc_s[16][C1];   // aggregated (incl. self, *ic)
    __shared__ float h_s[16][C1];     // unscaled h for identity2
    int tid = threadIdx.x;

    for (int i = tid; i < C1 * 128; i += 256) {
        int k = i >> 7, c = i & 127;
        Wc[k][c] = (c < 64) ? W2[k * C2 + c] : T2[k * C2 + (c - 64)];
    }

    int nl = tid >> 4, ch = tid & 15;
    int node = blockIdx.x * 16 + nl;
    float acc = 0.f, hval = 0.f;
    if (node < n) {
        int beg = offs[node], end = beg + cnt[node];
        float a0 = 0.f, a1 = 0.f, a2 = 0.f, a3 = 0.f;
        int p = beg;
        for (; p + 3 < end; p += 4) {
            int s0 = sorted[p], s1 = sorted[p + 1], s2 = sorted[p + 2], s3 = sorted[p + 3];
            a0 += hs[s0 * C1 + ch];
            a1 += hs[s1 * C1 + ch];
            a2 += hs[s2 * C1 + ch];
            a3 += hs[s3 * C1 + ch];
        }
        for (; p < end; ++p) a0 += hs[sorted[p] * C1 + ch];
        int idx = node * C1 + ch;
        acc = (a0 + a1 + a2 + a3 + hs[idx]) * inv[node];
        hval = h[idx];
    }
    acc_s[nl][ch] = acc;
    h_s[nl][ch]   = hval;
    __syncthreads();

    int och = tid & 63, grp = tid >> 6;
    #pragma unroll
    for (int q = 0; q < 4; ++q) {
        int nl2 = grp * 4 + q;
        int node2 = blockIdx.x * 16 + nl2;
        if (node2 >= n) continue;
        float s1v = b2[och], s2v = t2b[och];
        #pragma unroll
        for (int k = 0; k < C1; ++k) {
            s1v += acc_s[nl2][k] * Wc[k][och];
            s2v += h_s[nl2][k]   * Wc[k][och + 64];
        }
        out[node2 * C2 + och] = fmaxf(s1v, 0.f) + s2v;
    }
}

extern "C" void kernel_launch(void* const* d_in, const int* in_sizes, int n_in,
                              void* d_out, int out_size, void* d_ws, size_t ws_size,
                              hipStream_t stream) {
    const float* x   = (const float*)d_in[0];
    const int*   ei  = (const int*)d_in[1];
    const float* W1  = (const float*)d_in[2];
    const float* b1  = (const float*)d_in[3];
    const float* W2  = (const float*)d_in[4];
    const float* b2  = (const float*)d_in[5];
    const float* T1  = (const float*)d_in[6];
    const float* t1b = (const float*)d_in[7];
    const float* T2  = (const float*)d_in[8];
    const float* t2b = (const float*)d_in[9];
    float* out = (float*)d_out;

    const int n = in_sizes[0] / INCH;       // 100000
    const int e = in_sizes[1] / 2;          // 3200000
    const int* row = ei;
    const int* col = ei + e;

    // workspace layout
    char* ws = (char*)d_ws;
    int*   sorted = (int*)ws;                         ws += (size_t)e * 4;   // 12.8 MB
    int*   cnt    = (int*)ws;                         ws += (size_t)n * 4;
    int*   cursor = (int*)ws;                         ws += (size_t)n * 4;
    int*   offs   = (int*)ws;                         ws += (size_t)n * 4;
    int*   bsum   = (int*)ws;                         ws += 256 * 4;
    float* inv    = (float*)ws;                       ws += (size_t)n * 4;
    float* xW1s   = (float*)ws;                       ws += (size_t)n * C1 * 4;
    float* xT1    = (float*)ws;                       ws += (size_t)n * C1 * 4;
    float* h      = (float*)ws;                       ws += (size_t)n * C1 * 4;
    float* hs     = (float*)ws;                       ws += (size_t)n * C1 * 4;

    const int B = 256;
    const int nb_scan = (n + SCAN_B - 1) / SCAN_B;    // 196
    const int nslices = 768;                          // 6144 scatter blocks

    init_kernel   <<<(n + B - 1) / B, B, 0, stream>>>(cnt, n);
    hist_kernel   <<<(e / 4 + B - 1) / B, B, 0, stream>>>(col, cnt, e);
    invsqrt_kernel<<<(n + B - 1) / B, B, 0, stream>>>(cnt, inv, n);

    scan_local_kernel<<<nb_scan, SCAN_B, 0, stream>>>(cnt, offs, bsum, n);
    scan_bsum_kernel <<<1, 256, 0, stream>>>(bsum, nb_scan);
    scan_add_kernel  <<<nb_scan, SCAN_B, 0, stream>>>(offs, cursor, bsum, n);

    scatter_kernel<<<nslices * NRANGE, B, 0, stream>>>(row, col, cursor, sorted, e, n, nslices);

    linear1_kernel <<<(n + 15) / 16, B, 0, stream>>>(x, W1, T1, t1b, inv, xW1s, xT1, n);
    agg1_csr_kernel<<<(n + 15) / 16, B, 0, stream>>>(sorted, offs, cnt, inv, xW1s, xT1, b1, h, hs, n);

    agg2_fused_kernel<<<(n + 15) / 16, B, 0, stream>>>(sorted, offs, cnt, inv, hs, h,
                                                       W2, T2, b2, t2b, out, n);
}

// Round 5
// 471.803 us; speedup vs baseline: 2.5973x; 1.1519x over previous
//
#include <hip/hip_runtime.h>

#define INCH 128
#define C1   16
#define C2   64
#define SCAN_B 512   // elements per scan block
#define NRANGE 8     // dst-range partitions for scatter (XCD count)

typedef int iv4 __attribute__((ext_vector_type(4)));

// ---------------- init: zero cnt -------------------------------------------
__global__ void init_kernel(int* __restrict__ cnt, int n) {
    int tid = blockIdx.x * blockDim.x + threadIdx.x;
    if (tid < n) cnt[tid] = 0;
}

// ---------------- histogram + rank capture ---------------------------------
// rank[i] = #earlier edges with same dst  (atomicAdd return value).
// Plain (non-NT) reads so col primes L3 for the scatter's re-reads.
__global__ void hist_kernel(const int* __restrict__ col, int* __restrict__ cnt,
                            int* __restrict__ rank, int e) {
    int tid = blockIdx.x * blockDim.x + threadIdx.x;
    int e4 = e >> 2;
    if (tid < e4) {
        iv4 c4 = ((const iv4*)col)[tid];
        iv4 r4;
        r4.x = atomicAdd(&cnt[c4.x], 1);
        r4.y = atomicAdd(&cnt[c4.y], 1);
        r4.z = atomicAdd(&cnt[c4.z], 1);
        r4.w = atomicAdd(&cnt[c4.w], 1);
        ((iv4*)rank)[tid] = r4;
    }
    int rem = e4 * 4 + tid;
    if (tid < (e & 3)) rank[rem] = atomicAdd(&cnt[col[rem]], 1);
}

// ---------------- scan level 1 (+ fused inv_sqrt of deg) -------------------
__global__ __launch_bounds__(SCAN_B) void scan_local_kernel(
    const int* __restrict__ cnt, int* __restrict__ offs, int* __restrict__ bsum,
    float* __restrict__ inv, int n)
{
    __shared__ int tmp[SCAN_B];
    int gid = blockIdx.x * SCAN_B + threadIdx.x;
    int v = (gid < n) ? cnt[gid] : 0;
    if (gid < n) inv[gid] = rsqrtf((float)(v + 1));   // +1 self loop
    tmp[threadIdx.x] = v;
    __syncthreads();
    for (int off = 1; off < SCAN_B; off <<= 1) {
        int t = (threadIdx.x >= off) ? tmp[threadIdx.x - off] : 0;
        __syncthreads();
        tmp[threadIdx.x] += t;
        __syncthreads();
    }
    if (gid < n) offs[gid] = tmp[threadIdx.x] - v;        // exclusive
    if (threadIdx.x == SCAN_B - 1) bsum[blockIdx.x] = tmp[SCAN_B - 1];
}

__global__ __launch_bounds__(256) void scan_bsum_kernel(int* __restrict__ bsum, int nb) {
    __shared__ int tmp[256];
    int v = (threadIdx.x < nb) ? bsum[threadIdx.x] : 0;
    tmp[threadIdx.x] = v;
    __syncthreads();
    for (int off = 1; off < 256; off <<= 1) {
        int t = (threadIdx.x >= off) ? tmp[threadIdx.x - off] : 0;
        __syncthreads();
        tmp[threadIdx.x] += t;
        __syncthreads();
    }
    if (threadIdx.x < nb) bsum[threadIdx.x] = tmp[threadIdx.x] - v;  // exclusive
}

__global__ __launch_bounds__(SCAN_B) void scan_add_kernel(
    int* __restrict__ offs, const int* __restrict__ bsum, int n)
{
    int gid = blockIdx.x * SCAN_B + threadIdx.x;
    if (gid < n) offs[gid] += bsum[blockIdx.x];
}

// ---------------- atomic-free dst-range-partitioned scatter ----------------
// block (slice s, residue r): reads edge chunk s, writes only edges with
// dst in range r -> sorted stores confined to a 1.6 MB region per residue
// (one XCD's L2 under round-robin dispatch). Position = offs[c] + rank[i]
// is fully determined: no atomics in this kernel.
__global__ __launch_bounds__(256) void scatter_kernel(
    const int* __restrict__ row, const int* __restrict__ col,
    const int* __restrict__ rank, const int* __restrict__ offs,
    int* __restrict__ sorted, int e, int n, int nslices)
{
    int r = blockIdx.x & (NRANGE - 1);
    int s = blockIdx.x >> 3;
    int lo = (int)((long)n * r / NRANGE);
    int hi = (int)((long)n * (r + 1) / NRANGE);
    int e4 = e >> 2;
    long b0 = (long)s * e4 / nslices;
    long b1 = (long)(s + 1) * e4 / nslices;
    const iv4* row4 = (const iv4*)row;
    const iv4* col4 = (const iv4*)col;
    const iv4* rnk4 = (const iv4*)rank;
    for (long i = b0 + threadIdx.x; i < b1; i += blockDim.x) {
        iv4 c4 = col4[i];
        iv4 k4 = rnk4[i];
        iv4 r4 = row4[i];
        #pragma unroll
        for (int k = 0; k < 4; ++k) {
            int c = c4[k];
            if (c >= lo && c < hi) sorted[offs[c] + k4[k]] = r4[k];
        }
    }
    if (s == 0) {   // tail (e % 4)
        for (int i = e4 * 4 + threadIdx.x; i < e; i += blockDim.x) {
            int c = col[i];
            if (c >= lo && c < hi) sorted[offs[c] + rank[i]] = row[i];
        }
    }
}

// ---------------- linear1: xW1s = (x@W1)*inv, xT1 = x@t1_W + t1_b ----------
__global__ __launch_bounds__(256) void linear1_kernel(
    const float* __restrict__ x, const float* __restrict__ W1,
    const float* __restrict__ T1, const float* __restrict__ t1b,
    const float* __restrict__ inv,
    float* __restrict__ xW1s, float* __restrict__ xT1, int n)
{
    __shared__ float Wc[INCH][32];        // [:,0:16]=W1, [:,16:32]=t1_W
    __shared__ float xs[16][INCH + 4];
    int tid = threadIdx.x;

    for (int i = tid; i < INCH * C1; i += 256) {
        int k = i / C1, c = i % C1;
        Wc[k][c]      = W1[i];
        Wc[k][c + 16] = T1[i];
    }
    int node0 = blockIdx.x * 16;
    for (int i = tid; i < 16 * (INCH / 4); i += 256) {
        int r = i / (INCH / 4);
        int cc = i % (INCH / 4);
        int node = node0 + r;
        float4 v = make_float4(0.f, 0.f, 0.f, 0.f);
        if (node < n) v = ((const float4*)x)[(size_t)node * (INCH / 4) + cc];
        ((float4*)&xs[r][0])[cc] = v;
    }
    __syncthreads();

    int ch = tid & 15, nl = tid >> 4;
    int node = node0 + nl;
    if (node >= n) return;
    float a1 = 0.f, a2 = 0.f;
    #pragma unroll
    for (int k = 0; k < INCH; ++k) {
        float xv = xs[nl][k];
        a1 += xv * Wc[k][ch];
        a2 += xv * Wc[k][ch + 16];
    }
    xW1s[node * C1 + ch] = a1 * inv[node];   // pre-scaled by inv[src]
    xT1[node * C1 + ch]  = a2 + t1b[ch];
}

// ---------------- agg1 CSR + fused epilogue1 -------------------------------
__global__ __launch_bounds__(256) void agg1_csr_kernel(
    const int* __restrict__ sorted, const int* __restrict__ offs,
    const int* __restrict__ cnt, const float* __restrict__ inv,
    const float* __restrict__ xW1s, const float* __restrict__ xT1,
    const float* __restrict__ b1,
    float* __restrict__ h, float* __restrict__ hs, int n)
{
    int node = blockIdx.x * 16 + (threadIdx.x >> 4);
    int ch = threadIdx.x & 15;
    if (node >= n) return;
    int beg = offs[node], end = beg + cnt[node];
    float ic = inv[node];
    float a0 = 0.f, a1 = 0.f, a2 = 0.f, a3 = 0.f;
    int p = beg;
    for (; p + 3 < end; p += 4) {
        int s0 = sorted[p], s1 = sorted[p + 1], s2 = sorted[p + 2], s3 = sorted[p + 3];
        a0 += xW1s[s0 * C1 + ch];
        a1 += xW1s[s1 * C1 + ch];
        a2 += xW1s[s2 * C1 + ch];
        a3 += xW1s[s3 * C1 + ch];
    }
    for (; p < end; ++p) a0 += xW1s[sorted[p] * C1 + ch];
    int idx = node * C1 + ch;
    float v = (a0 + a1 + a2 + a3 + xW1s[idx]) * ic + b1[ch];
    float hv = fmaxf(v, 0.f) + xT1[idx];
    h[idx]  = hv;
    hs[idx] = hv * ic;
}

// ---------------- agg2 fused: CSR agg (16ch) + 16->64 linears + epilogue ---
__global__ __launch_bounds__(256) void agg2_fused_kernel(
    const int* __restrict__ sorted, const int* __restrict__ offs,
    const int* __restrict__ cnt, const float* __restrict__ inv,
    const float* __restrict__ hs, const float* __restrict__ h,
    const float* __restrict__ W2, const float* __restrict__ T2,
    const float* __restrict__ b2, const float* __restrict__ t2b,
    float* __restrict__ out, int n)
{
    __shared__ float Wc[C1][128];     // [:,0:64]=W2, [:,64:128]=t2_W
    __shared__ float acc_s[16][C1];   // aggregated (incl. self, *ic)
    __shared__ float h_s[16][C1];     // unscaled h for identity2
    int tid = threadIdx.x;

    for (int i = tid; i < C1 * 128; i += 256) {
        int k = i >> 7, c = i & 127;
        Wc[k][c] = (c < 64) ? W2[k * C2 + c] : T2[k * C2 + (c - 64)];
    }

    int nl = tid >> 4, ch = tid & 15;
    int node = blockIdx.x * 16 + nl;
    float acc = 0.f, hval = 0.f;
    if (node < n) {
        int beg = offs[node], end = beg + cnt[node];
        float a0 = 0.f, a1 = 0.f, a2 = 0.f, a3 = 0.f;
        int p = beg;
        for (; p + 3 < end; p += 4) {
            int s0 = sorted[p], s1 = sorted[p + 1], s2 = sorted[p + 2], s3 = sorted[p + 3];
            a0 += hs[s0 * C1 + ch];
            a1 += hs[s1 * C1 + ch];
            a2 += hs[s2 * C1 + ch];
            a3 += hs[s3 * C1 + ch];
        }
        for (; p < end; ++p) a0 += hs[sorted[p] * C1 + ch];
        int idx = node * C1 + ch;
        acc = (a0 + a1 + a2 + a3 + hs[idx]) * inv[node];
        hval = h[idx];
    }
    acc_s[nl][ch] = acc;
    h_s[nl][ch]   = hval;
    __syncthreads();

    int och = tid & 63, grp = tid >> 6;
    #pragma unroll
    for (int q = 0; q < 4; ++q) {
        int nl2 = grp * 4 + q;
        int node2 = blockIdx.x * 16 + nl2;
        if (node2 >= n) continue;
        float s1v = b2[och], s2v = t2b[och];
        #pragma unroll
        for (int k = 0; k < C1; ++k) {
            s1v += acc_s[nl2][k] * Wc[k][och];
            s2v += h_s[nl2][k]   * Wc[k][och + 64];
        }
        out[node2 * C2 + och] = fmaxf(s1v, 0.f) + s2v;
    }
}

extern "C" void kernel_launch(void* const* d_in, const int* in_sizes, int n_in,
                              void* d_out, int out_size, void* d_ws, size_t ws_size,
                              hipStream_t stream) {
    const float* x   = (const float*)d_in[0];
    const int*   ei  = (const int*)d_in[1];
    const float* W1  = (const float*)d_in[2];
    const float* b1  = (const float*)d_in[3];
    const float* W2  = (const float*)d_in[4];
    const float* b2  = (const float*)d_in[5];
    const float* T1  = (const float*)d_in[6];
    const float* t1b = (const float*)d_in[7];
    const float* T2  = (const float*)d_in[8];
    const float* t2b = (const float*)d_in[9];
    float* out = (float*)d_out;

    const int n = in_sizes[0] / INCH;       // 100000
    const int e = in_sizes[1] / 2;          // 3200000
    const int* row = ei;
    const int* col = ei + e;

    // workspace layout
    char* ws = (char*)d_ws;
    int*   sorted = (int*)ws;                         ws += (size_t)e * 4;   // 12.8 MB
    int*   rank   = (int*)ws;                         ws += (size_t)e * 4;   // 12.8 MB
    int*   cnt    = (int*)ws;                         ws += (size_t)n * 4;
    int*   offs   = (int*)ws;                         ws += (size_t)n * 4;
    int*   bsum   = (int*)ws;                         ws += 256 * 4;
    float* inv    = (float*)ws;                       ws += (size_t)n * 4;
    float* xW1s   = (float*)ws;                       ws += (size_t)n * C1 * 4;
    float* xT1    = (float*)ws;                       ws += (size_t)n * C1 * 4;
    float* h      = (float*)ws;                       ws += (size_t)n * C1 * 4;
    float* hs     = (float*)ws;                       ws += (size_t)n * C1 * 4;

    const int B = 256;
    const int nb_scan = (n + SCAN_B - 1) / SCAN_B;    // 196
    const int nslices = 512;                          // 4096 scatter blocks

    init_kernel<<<(n + B - 1) / B, B, 0, stream>>>(cnt, n);
    hist_kernel<<<(e / 4 + B - 1) / B, B, 0, stream>>>(col, cnt, rank, e);

    scan_local_kernel<<<nb_scan, SCAN_B, 0, stream>>>(cnt, offs, bsum, inv, n);
    scan_bsum_kernel <<<1, 256, 0, stream>>>(bsum, nb_scan);
    scan_add_kernel  <<<nb_scan, SCAN_B, 0, stream>>>(offs, bsum, n);

    scatter_kernel<<<nslices * NRANGE, B, 0, stream>>>(row, col, rank, offs, sorted, e, n, nslices);

    linear1_kernel <<<(n + 15) / 16, B, 0, stream>>>(x, W1, T1, t1b, inv, xW1s, xT1, n);
    agg1_csr_kernel<<<(n + 15) / 16, B, 0, stream>>>(sorted, offs, cnt, inv, xW1s, xT1, b1, h, hs, n);

    agg2_fused_kernel<<<(n + 15) / 16, B, 0, stream>>>(sorted, offs, cnt, inv, hs, h,
                                                       W2, T2, b2, t2b, out, n);
}